// Round 2
// 198.151 us; speedup vs baseline: 1.0751x; 1.0751x over previous
//
#include <hip/hip_runtime.h>
#include <stdint.h>

// SpectralFreqTimeConv2D: B=32, N=128, C=32, M=17. Truncated-DFT factorization.
// R5: LDS twiddle tables replace rotation recurrences (A/C/fwd_y/inv_y),
// stage-A balanced to 18 units (no double-duty waves), stage-B float4 weight
// loads, k_tproj 4-acc unroll.

#define TWO_PI_OVER_128 0.04908738521234052f

// ---------------- K0: t1/t2 = t_emb @ (k_real, k_imag) -> tbuf[which][b][i][2]
__global__ __launch_bounds__(128) void k_tproj(
    const float* __restrict__ temb, const float* __restrict__ k1r, const float* __restrict__ k1i,
    const float* __restrict__ k2r, const float* __restrict__ k2i, float* __restrict__ tbuf)
{
    int b = blockIdx.x, tid = threadIdx.x;
    __shared__ float ts[256];
    for (int d = tid; d < 256; d += 128) ts[d] = temb[b * 256 + d];
    __syncthreads();
    if (tid < 68) {
        int which = (tid >= 34) ? 1 : 0;
        int rem = tid - which * 34;
        int i = rem >> 1, part = rem & 1;
        const float* kp = which ? (part ? k2i : k2r) : (part ? k1i : k1r);
        float a0 = 0.f, a1 = 0.f, a2 = 0.f, a3 = 0.f;
        for (int d = 0; d < 256; d += 4) {
            a0 = fmaf(ts[d],     kp[(d)     * 17 + i], a0);
            a1 = fmaf(ts[d + 1], kp[(d + 1) * 17 + i], a1);
            a2 = fmaf(ts[d + 2], kp[(d + 2) * 17 + i], a2);
            a3 = fmaf(ts[d + 3], kp[(d + 3) * 17 + i], a3);
        }
        tbuf[((which * 32 + b) * 17 + i) * 2 + part] = (a0 + a1) + (a2 + a3);
    }
}

// ---------------- K1: y-axis DFT with y<->128-y folding. block = (b,x), 64 thr.
// Twiddles from LDS table cst[k] = (cos(2πk/128), -sin(2πk/128)).
__global__ __launch_bounds__(64) void k_fwd_y(const float* __restrict__ x, float2* __restrict__ T1)
{
    int blk = blockIdx.x;
    int b = blk >> 7, xr = blk & 127;
    __shared__ float xs[128 * 32];
    __shared__ float2 cst[128];
    int tid = threadIdx.x;
    {
        float s0, c0; sincosf(TWO_PI_OVER_128 * (float)tid, &s0, &c0);
        cst[tid] = make_float2(c0, -s0);
        float s1, c1; sincosf(TWO_PI_OVER_128 * (float)(tid + 64), &s1, &c1);
        cst[tid + 64] = make_float2(c1, -s1);
    }
    const float4* xv = (const float4*)(x + ((size_t)blk << 12));
    float4* xs4 = (float4*)xs;
#pragma unroll
    for (int i = 0; i < 16; ++i) xs4[tid + (i << 6)] = xv[tid + (i << 6)];
    __syncthreads();
    for (int i = tid; i < 2016; i += 64) {
        int y = (i >> 5) + 1, c = i & 31;
        float a = xs[(y << 5) + c], q = xs[((128 - y) << 5) + c];
        xs[(y << 5) + c] = a + q;
        xs[((128 - y) << 5) + c] = a - q;
    }
    __syncthreads();
    int jg = tid >> 3, cg = tid & 7, c0 = cg << 2;
    float re[2][4] = {{0,0,0,0},{0,0,0,0}}, im[2][4] = {{0,0,0,0},{0,0,0,0}};
    int j0 = jg, j1 = jg + 8;
    int idx0 = 0, idx1 = 0;
    for (int y = 1; y <= 63; ++y) {
        idx0 = (idx0 + j0) & 127;
        idx1 = (idx1 + j1) & 127;
        float2 w0 = cst[idx0], w1 = cst[idx1];
        float4 s = *(const float4*)&xs[(y << 5) + c0];
        float4 d = *(const float4*)&xs[((128 - y) << 5) + c0];
        re[0][0] = fmaf(s.x, w0.x, re[0][0]);
        re[0][1] = fmaf(s.y, w0.x, re[0][1]);
        re[0][2] = fmaf(s.z, w0.x, re[0][2]);
        re[0][3] = fmaf(s.w, w0.x, re[0][3]);
        im[0][0] = fmaf(d.x, w0.y, im[0][0]);
        im[0][1] = fmaf(d.y, w0.y, im[0][1]);
        im[0][2] = fmaf(d.z, w0.y, im[0][2]);
        im[0][3] = fmaf(d.w, w0.y, im[0][3]);
        re[1][0] = fmaf(s.x, w1.x, re[1][0]);
        re[1][1] = fmaf(s.y, w1.x, re[1][1]);
        re[1][2] = fmaf(s.z, w1.x, re[1][2]);
        re[1][3] = fmaf(s.w, w1.x, re[1][3]);
        im[1][0] = fmaf(d.x, w1.y, im[1][0]);
        im[1][1] = fmaf(d.y, w1.y, im[1][1]);
        im[1][2] = fmaf(d.z, w1.y, im[1][2]);
        im[1][3] = fmaf(d.w, w1.y, im[1][3]);
    }
    const float s_ = 1.f / 16384.f;
    float x0[4], x64[4];
    *(float4*)x0  = *(const float4*)&xs[c0];
    *(float4*)x64 = *(const float4*)&xs[(64 << 5) + c0];
#pragma unroll
    for (int t = 0; t < 2; ++t) {
        int j = jg + t * 8;
        float sg = (j & 1) ? -1.f : 1.f;
        float2* p = T1 + (((size_t)(b * 17 + j) * 128 + xr) << 5) + c0;
        float4 v0 = make_float4((re[t][0] + x0[0] + sg * x64[0]) * s_, im[t][0] * s_,
                                (re[t][1] + x0[1] + sg * x64[1]) * s_, im[t][1] * s_);
        float4 v1 = make_float4((re[t][2] + x0[2] + sg * x64[2]) * s_, im[t][2] * s_,
                                (re[t][3] + x0[3] + sg * x64[3]) * s_, im[t][3] * s_);
        ((float4*)p)[0] = v0; ((float4*)p)[1] = v1;
    }
    if (jg == 0) {
        float re2[4] = {0,0,0,0}, im2[4] = {0,0,0,0};
        int idx2 = 0;
        for (int y = 1; y <= 63; ++y) {
            idx2 = (idx2 + 16) & 127;
            float2 w = cst[idx2];
            float4 s = *(const float4*)&xs[(y << 5) + c0];
            float4 d = *(const float4*)&xs[((128 - y) << 5) + c0];
            re2[0] = fmaf(s.x, w.x, re2[0]); re2[1] = fmaf(s.y, w.x, re2[1]);
            re2[2] = fmaf(s.z, w.x, re2[2]); re2[3] = fmaf(s.w, w.x, re2[3]);
            im2[0] = fmaf(d.x, w.y, im2[0]); im2[1] = fmaf(d.y, w.y, im2[1]);
            im2[2] = fmaf(d.z, w.y, im2[2]); im2[3] = fmaf(d.w, w.y, im2[3]);
        }
        float2* p = T1 + (((size_t)(b * 17 + 16) * 128 + xr) << 5) + c0;
        float4 v0 = make_float4((re2[0] + x0[0] + x64[0]) * s_, im2[0] * s_,
                                (re2[1] + x0[1] + x64[1]) * s_, im2[1] * s_);
        float4 v1 = make_float4((re2[2] + x0[2] + x64[2]) * s_, im2[2] * s_,
                                (re2[3] + x0[3] + x64[3]) * s_, im2[3] * s_);
        ((float4*)p)[0] = v0; ((float4*)p)[1] = v1;
    }
}

// ---------------- K2': fused x-DFT + mix + inverse-x. block=(b,j), 512 thr.
// Stage A: 18 balanced units (16 pairs + f=0 + f=111), table twiddles.
// Stage B: float4 weight loads, (ii, o-quad) mapping, 272 threads.
// Stage C: table twiddles (6 VALU per i instead of 10).
__global__ __launch_bounds__(512) void k_mid_fused(
    const float2* __restrict__ T1, const float* __restrict__ w1r, const float* __restrict__ w1i,
    const float* __restrict__ w2r, const float* __restrict__ w2i,
    const float* __restrict__ tbuf, float2* __restrict__ U)
{
    int blk = blockIdx.x;
    int b = blk / 17, j = blk - b * 17;
    __shared__ float4 Ts4[2048];          // 32 KB tile; reused as Ys after stage A
    __shared__ float2 Xf[34 * 32];        // 8.5 KB
    __shared__ float2 cst[128];           // (cos, sin) table
    int tid = threadIdx.x;
    const float4* s4 = (const float4*)(T1 + (size_t)blk * 4096);
    for (int i = tid; i < 2048; i += 512) Ts4[i] = s4[i];
    if (tid < 128) {
        float s, c; sincosf(TWO_PI_OVER_128 * (float)tid, &s, &c);
        cst[tid] = make_float2(c, s);
    }
    __syncthreads();
    // fold x<->128-x: row x <- S=T[x]+T[128-x]; row 128-x <- D=T[x]-T[128-x]
    for (int i = tid; i < 1008; i += 512) {
        int xx = (i >> 4) + 1, cp = i & 15;
        float4 a = Ts4[(xx << 4) + cp], q = Ts4[((128 - xx) << 4) + cp];
        Ts4[(xx << 4) + cp] = make_float4(a.x + q.x, a.y + q.y, a.z + q.z, a.w + q.w);
        Ts4[((128 - xx) << 4) + cp] = make_float4(a.x - q.x, a.y - q.y, a.z - q.z, a.w - q.w);
    }
    __syncthreads();
    // ---- stage A: 18 units x 16 cp = 288 threads, balanced
    if (tid < 288) {
        int cp = tid & 15, u = tid >> 4;
        float4 t0 = Ts4[cp], t64 = Ts4[(64 << 4) + cp];
        if (u < 16) {
            int f = u + 1;
            int idx = 0;
            float P0=0,Q0=0,R0=0,T0=0,P1=0,Q1=0,R1=0,T1a=0;
            for (int xx = 1; xx <= 63; ++xx) {
                idx = (idx + f) & 127;
                float2 w = cst[idx];
                float4 S = Ts4[(xx << 4) + cp];
                float4 D = Ts4[((128 - xx) << 4) + cp];
                P0 = fmaf(S.x, w.x, P0); Q0 = fmaf(D.y, w.y, Q0);
                R0 = fmaf(S.y, w.x, R0); T0 = fmaf(D.x, w.y, T0);
                P1 = fmaf(S.z, w.x, P1); Q1 = fmaf(D.w, w.y, Q1);
                R1 = fmaf(S.w, w.x, R1); T1a = fmaf(D.z, w.y, T1a);
            }
            float sg = (f & 1) ? -1.f : 1.f;
            float b0r = t0.x + sg * t64.x, b0i = t0.y + sg * t64.y;
            float b1r = t0.z + sg * t64.z, b1i = t0.w + sg * t64.w;
            int ia = f, ib = 34 - f;
            Xf[ia * 32 + cp*2]   = make_float2(P0 + Q0 + b0r, R0 - T0 + b0i);
            Xf[ia * 32 + cp*2+1] = make_float2(P1 + Q1 + b1r, R1 - T1a + b1i);
            Xf[ib * 32 + cp*2]   = make_float2(P0 - Q0 + b0r, R0 + T0 + b0i);
            Xf[ib * 32 + cp*2+1] = make_float2(P1 - Q1 + b1r, R1 + T1a + b1i);
        } else if (u == 16) {                       // f=0 (ii=0)
            float A0=0,B0=0,A1=0,B1=0;
            for (int xx = 1; xx <= 63; ++xx) {
                float4 S = Ts4[(xx << 4) + cp];
                A0 += S.x; B0 += S.y; A1 += S.z; B1 += S.w;
            }
            Xf[cp*2]   = make_float2(A0 + t0.x + t64.x, B0 + t0.y + t64.y);
            Xf[cp*2+1] = make_float2(A1 + t0.z + t64.z, B1 + t0.w + t64.w);
        } else {                                    // u == 17: f=111 (ii=17)
            int idx = 0;
            float p0=0,q0=0,r0=0,s0=0,p1=0,q1=0,r1=0,s1=0;
            for (int xx = 1; xx <= 63; ++xx) {
                idx = (idx + 111) & 127;
                float2 w = cst[idx];
                float4 S = Ts4[(xx << 4) + cp];
                float4 D = Ts4[((128 - xx) << 4) + cp];
                p0 = fmaf(S.x, w.x, p0); q0 = fmaf(D.y, w.y, q0);
                r0 = fmaf(S.y, w.x, r0); s0 = fmaf(D.x, w.y, s0);
                p1 = fmaf(S.z, w.x, p1); q1 = fmaf(D.w, w.y, q1);
                r1 = fmaf(S.w, w.x, r1); s1 = fmaf(D.z, w.y, s1);
            }
            float c0r = t0.x - t64.x, c0i = t0.y - t64.y;
            float c1r = t0.z - t64.z, c1i = t0.w - t64.w;
            Xf[17*32 + cp*2]   = make_float2(p0 + q0 + c0r, r0 - s0 + c0i);
            Xf[17*32 + cp*2+1] = make_float2(p1 + q1 + c1r, r1 - s1 + c1i);
        }
    }
    __syncthreads();
    // ---- stage B: Ys[ii][o] = t * sum_c Xf[ii][c] * w[irow,j,c,o], float4 loads
    float2* Ys = (float2*)Ts4;
    if (tid < 272) {
        int oq = tid & 7, ii = tid >> 3;
        int o0 = oq << 2;
        int irow = (ii < 17) ? ii : ii - 17;
        const float* wr = ((ii < 17) ? w1r : w2r) + ((irow * 17 + j) << 10) + o0;
        const float* wi = ((ii < 17) ? w1i : w2i) + ((irow * 17 + j) << 10) + o0;
        float ar0=0,ai0=0,ar1=0,ai1=0,ar2=0,ai2=0,ar3=0,ai3=0;
#pragma unroll 4
        for (int c = 0; c < 32; ++c) {
            float2 xv = Xf[ii * 32 + c];
            float4 wre = *(const float4*)(wr + (c << 5));
            float4 wim = *(const float4*)(wi + (c << 5));
            ar0 = fmaf(xv.x, wre.x, ar0); ar0 = fmaf(-xv.y, wim.x, ar0);
            ai0 = fmaf(xv.x, wim.x, ai0); ai0 = fmaf( xv.y, wre.x, ai0);
            ar1 = fmaf(xv.x, wre.y, ar1); ar1 = fmaf(-xv.y, wim.y, ar1);
            ai1 = fmaf(xv.x, wim.y, ai1); ai1 = fmaf( xv.y, wre.y, ai1);
            ar2 = fmaf(xv.x, wre.z, ar2); ar2 = fmaf(-xv.y, wim.z, ar2);
            ai2 = fmaf(xv.x, wim.z, ai2); ai2 = fmaf( xv.y, wre.z, ai2);
            ar3 = fmaf(xv.x, wre.w, ar3); ar3 = fmaf(-xv.y, wim.w, ar3);
            ai3 = fmaf(xv.x, wim.w, ai3); ai3 = fmaf( xv.y, wre.w, ai3);
        }
        int which = (ii >= 17) ? 1 : 0;
        const float* tp = tbuf + ((which * 32 + b) * 17 + irow) * 2;
        float tr = tp[0], ti = tp[1];
        float2* yp = Ys + ii * 32 + o0;
        float4 y01 = make_float4(ar0 * tr - ai0 * ti, ar0 * ti + ai0 * tr,
                                 ar1 * tr - ai1 * ti, ar1 * ti + ai1 * tr);
        float4 y23 = make_float4(ar2 * tr - ai2 * ti, ar2 * ti + ai2 * tr,
                                 ar3 * tr - ai3 * ti, ar3 * ti + ai3 * tr);
        ((float4*)yp)[0] = y01;
        ((float4*)yp)[1] = y23;
    }
    __syncthreads();
    // ---- stage C: U[x], U[128-x] pairs; x=0 and x=64 singles; table twiddles
    {
        int o = tid & 31, g = tid >> 5;              // g 0..15
        float yr[34], yi[34];
#pragma unroll
        for (int i = 0; i < 34; ++i) { float2 v = Ys[i * 32 + o]; yr[i] = v.x; yi[i] = v.y; }
        float2* Ub = U + ((size_t)b * 128 * 17 + j) * 32 + o;
        if (g == 0) {
            float sr = 0.f, si = 0.f;
#pragma unroll
            for (int i = 0; i < 34; ++i) { sr += yr[i]; si += yi[i]; }
            Ub[0] = make_float2(sr, si);
        }
        for (int k = 0; k < 4; ++k) {
            int x = 1 + g + (k << 4);
            if (x == 64) {
                float sr = 0.f, si = 0.f;
#pragma unroll
                for (int i = 0; i < 34; ++i) {       // (-1)^f == (-1)^ii in both ranges
                    float sg2 = (i & 1) ? -1.f : 1.f;
                    sr = fmaf(sg2, yr[i], sr); si = fmaf(sg2, yi[i], si);
                }
                Ub[(size_t)64 * 544] = make_float2(sr, si);
            } else {
                float A1=0,A2=0,A3=0,A4=0;
                int idx = 0;
#pragma unroll
                for (int i = 0; i < 17; ++i) {
                    float2 w = cst[idx];
                    A1 = fmaf(yr[i], w.x, A1); A4 = fmaf(yr[i], w.y, A4);
                    A3 = fmaf(yi[i], w.x, A3); A2 = fmaf(yi[i], w.y, A2);
                    idx = (idx + x) & 127;
                }
                idx = (111 * x) & 127;
#pragma unroll
                for (int i = 17; i < 34; ++i) {
                    float2 w = cst[idx];
                    A1 = fmaf(yr[i], w.x, A1); A4 = fmaf(yr[i], w.y, A4);
                    A3 = fmaf(yi[i], w.x, A3); A2 = fmaf(yi[i], w.y, A2);
                    idx = (idx + x) & 127;
                }
                Ub[(size_t)x * 544]         = make_float2(A1 - A2, A3 + A4);
                Ub[(size_t)(128 - x) * 544] = make_float2(A1 + A2, A3 - A4);
            }
        }
    }
}

// ---------------- Fallback K2/K3 (R3 versions, used if ws too small) ----------
__global__ __launch_bounds__(256) void k_fwd_x_mix(
    const float2* __restrict__ T1, const float* __restrict__ w1r, const float* __restrict__ w1i,
    const float* __restrict__ w2r, const float* __restrict__ w2i,
    const float* __restrict__ tbuf, float2* __restrict__ Y)
{
    int blk = blockIdx.x;
    int b = blk / 17, j = blk - b * 17;
    __shared__ float4 Ts4[2048];
    __shared__ float2 Xf[34 * 32];
    int tid = threadIdx.x;
    const float4* s4 = (const float4*)(T1 + (size_t)blk * 4096);
    for (int i = tid; i < 2048; i += 256) Ts4[i] = s4[i];
    __syncthreads();
    {
        int cp = tid & 15, g = tid >> 4;
        int il[3] = {g, g + 16, g + 32};
        float stc[3], sts[3];
#pragma unroll
        for (int t = 0; t < 3; ++t) {
            int i = il[t];
            int f = (i < 17) ? i : i + 94;
            float a = -TWO_PI_OVER_128 * (float)(f & 127);
            sincosf(a, &sts[t], &stc[t]);
        }
        float cr[3] = {1.f, 1.f, 1.f}, ci[3] = {0.f, 0.f, 0.f};
        float r0[3] = {0,0,0}, i0[3] = {0,0,0}, r1[3] = {0,0,0}, i1[3] = {0,0,0};
        const float4* Tc = Ts4 + cp;
#pragma unroll 2
        for (int xx = 0; xx < 128; ++xx) {
            float4 tv = Tc[xx << 4];
#pragma unroll
            for (int t = 0; t < 3; ++t) {
                r0[t] += tv.x * cr[t] - tv.y * ci[t];
                i0[t] += tv.x * ci[t] + tv.y * cr[t];
                r1[t] += tv.z * cr[t] - tv.w * ci[t];
                i1[t] += tv.z * ci[t] + tv.w * cr[t];
                float nr = cr[t] * stc[t] - ci[t] * sts[t];
                ci[t] = fmaf(cr[t], sts[t], ci[t] * stc[t]);
                cr[t] = nr;
            }
        }
#pragma unroll
        for (int t = 0; t < 3; ++t) {
            int i = il[t];
            if (i < 34) {
                Xf[i * 32 + cp * 2]     = make_float2(r0[t], i0[t]);
                Xf[i * 32 + cp * 2 + 1] = make_float2(r1[t], i1[t]);
            }
        }
    }
    __syncthreads();
    {
        int o = tid & 31, gi = tid >> 5;
#pragma unroll
        for (int t = 0; t < 5; ++t) {
            int ii = gi + (t << 3);
            if (ii < 34) {
                int irow = (ii < 17) ? ii : ii - 17;
                const float* wr = ((ii < 17) ? w1r : w2r) + ((irow * 17 + j) << 10) + o;
                const float* wi = ((ii < 17) ? w1i : w2i) + ((irow * 17 + j) << 10) + o;
                float ar = 0.f, ai = 0.f;
#pragma unroll 8
                for (int cc2 = 0; cc2 < 32; ++cc2) {
                    float2 xv = Xf[ii * 32 + cc2];
                    float wre = wr[cc2 << 5];
                    float wim = wi[cc2 << 5];
                    ar += xv.x * wre - xv.y * wim;
                    ai += xv.x * wim + xv.y * wre;
                }
                int which = (ii >= 17) ? 1 : 0;
                const float* tp = tbuf + ((which * 32 + b) * 17 + irow) * 2;
                float tr = tp[0], ti = tp[1];
                Y[(size_t)blk * (34 * 32) + ii * 32 + o] =
                    make_float2(ar * tr - ai * ti, ar * ti + ai * tr);
            }
        }
    }
}

__global__ __launch_bounds__(256) void k_inv_x(const float2* __restrict__ Y, float2* __restrict__ U)
{
    int blk = blockIdx.x;
    int b = blk / 17, j = blk - b * 17;
    __shared__ float2 Ys[34 * 32];
    __shared__ float ct[128], st[128];
    int tid = threadIdx.x;
    if (tid < 128) {
        float a = TWO_PI_OVER_128 * (float)tid;
        sincosf(a, &st[tid], &ct[tid]);
    }
    const float2* src = Y + (size_t)blk * (34 * 32);
    for (int i = tid; i < 34 * 32; i += 256) Ys[i] = src[i];
    __syncthreads();
    int o = tid & 31, g = tid >> 5;
    float yr[34], yi[34];
#pragma unroll
    for (int i = 0; i < 34; ++i) { float2 v = Ys[i * 32 + o]; yr[i] = v.x; yi[i] = v.y; }
    for (int xi = 0; xi < 16; ++xi) {
        int xr = (xi << 3) + g;
        float cx = ct[xr], sx = st[xr];
        float cr = 1.f, ci = 0.f, re = 0.f, im = 0.f;
#pragma unroll
        for (int i = 0; i < 17; ++i) {
            re += yr[i] * cr - yi[i] * ci;
            im += yr[i] * ci + yi[i] * cr;
            float nr = cr * cx - ci * sx;
            ci = fmaf(cr, sx, ci * cx);
            cr = nr;
        }
        int k2 = (111 * xr) & 127;
        cr = ct[k2]; ci = st[k2];
#pragma unroll
        for (int i = 17; i < 34; ++i) {
            re += yr[i] * cr - yi[i] * ci;
            im += yr[i] * ci + yi[i] * cr;
            float nr = cr * cx - ci * sx;
            ci = fmaf(cr, sx, ci * cx);
            cr = nr;
        }
        U[(((size_t)(b * 128 + xr)) * 17 + j) * 32 + o] = make_float2(re, im);
    }
}

// ---------------- K4: inverse y-axis c2r with y<->128-y pairing. block=(b,x), 128 thr.
// Table twiddles cst[k] = (cos, sin); removes per-y sincosf + rotation.
__global__ __launch_bounds__(128) void k_inv_y(const float2* __restrict__ U, float* __restrict__ out)
{
    int blk = blockIdx.x;
    __shared__ float2 Us[17 * 32];
    __shared__ float2 cst[128];
    int tid = threadIdx.x;
    {
        float s, c; sincosf(TWO_PI_OVER_128 * (float)tid, &s, &c);
        cst[tid] = make_float2(c, s);
    }
    const float4* src4 = (const float4*)(U + (size_t)blk * 544);
    float4* Us4 = (float4*)Us;
    for (int i = tid; i < 272; i += 128) Us4[i] = src4[i];
    __syncthreads();
    int cg = tid & 15, yg = tid >> 4, c0 = cg << 1;
    float base0, base1;
    {
        float4 v = *(const float4*)&Us[c0];
        base0 = v.x; base1 = v.z;
    }
    float urr[16][2], uii[16][2];
#pragma unroll
    for (int jj = 1; jj <= 16; ++jj) {
        float4 v = *(const float4*)&Us[jj * 32 + c0];
        urr[jj-1][0] = 2.f * v.x; uii[jj-1][0] = 2.f * v.y;
        urr[jj-1][1] = 2.f * v.z; uii[jj-1][1] = 2.f * v.w;
    }
    float* op = out + ((size_t)blk << 12);
    for (int k = 0; k < 9; ++k) {
        int y = yg + (k << 3);
        if (y > 64) break;
        float A0 = 0.f, A1 = 0.f, B0 = 0.f, B1 = 0.f;
        int idx = y;
#pragma unroll
        for (int jj = 0; jj < 16; ++jj) {
            float2 w = cst[idx];
            A0 = fmaf(urr[jj][0], w.x, A0);
            B0 = fmaf(uii[jj][0], w.y, B0);
            A1 = fmaf(urr[jj][1], w.x, A1);
            B1 = fmaf(uii[jj][1], w.y, B1);
            idx = (idx + y) & 127;
        }
        *(float2*)&op[(y << 5) + c0] = make_float2(base0 + A0 - B0, base1 + A1 - B1);
        if (y > 0 && y < 64)
            *(float2*)&op[((128 - y) << 5) + c0] = make_float2(base0 + A0 + B0, base1 + A1 + B1);
    }
}

extern "C" void kernel_launch(void* const* d_in, const int* in_sizes, int n_in,
                              void* d_out, int out_size, void* d_ws, size_t ws_size,
                              hipStream_t stream)
{
    const float* x    = (const float*)d_in[0];
    const float* temb = (const float*)d_in[1];
    const float* w1r  = (const float*)d_in[2];
    const float* w1i  = (const float*)d_in[3];
    const float* w2r  = (const float*)d_in[4];
    const float* w2i  = (const float*)d_in[5];
    const float* k1r  = (const float*)d_in[6];
    const float* k1i  = (const float*)d_in[7];
    const float* k2r  = (const float*)d_in[8];
    const float* k2i  = (const float*)d_in[9];
    float* out = (float*)d_out;

    char* ws = (char*)d_ws;
    const size_t T1_BYTES = 17825792;                  // 32*17*128*32 float2
    const size_t NEED_FUSED = 2 * T1_BYTES + 8704;     // T1 + U + tbuf

    if (ws_size >= NEED_FUSED) {
        float2* T1 = (float2*)ws;
        float2* U  = (float2*)(ws + T1_BYTES);
        float*  tb = (float*)(ws + 2 * T1_BYTES);
        k_tproj    <<<32,   128, 0, stream>>>(temb, k1r, k1i, k2r, k2i, tb);
        k_fwd_y    <<<4096, 64,  0, stream>>>(x, T1);
        k_mid_fused<<<544,  512, 0, stream>>>(T1, w1r, w1i, w2r, w2i, tb, U);
        k_inv_y    <<<4096, 128, 0, stream>>>(U, out);
    } else {
        float2* T1 = (float2*)ws;
        float2* Yb = (float2*)(ws + T1_BYTES);
        float*  tb = (float*)(ws + T1_BYTES + 4734976);
        float2* U  = T1;
        k_tproj    <<<32,   128, 0, stream>>>(temb, k1r, k1i, k2r, k2i, tb);
        k_fwd_y    <<<4096, 64,  0, stream>>>(x, T1);
        k_fwd_x_mix<<<544,  256, 0, stream>>>(T1, w1r, w1i, w2r, w2i, tb, Yb);
        k_inv_x    <<<544,  256, 0, stream>>>(Yb, U);
        k_inv_y    <<<4096, 128, 0, stream>>>(U, out);
    }
}

// Round 4
// 187.591 us; speedup vs baseline: 1.1356x; 1.0563x over previous
//
#include <hip/hip_runtime.h>
#include <stdint.h>

// SpectralFreqTimeConv2D: B=32, N=128, C=32, M=17. Truncated-DFT factorization.
// R6: parity-fold quad-output inverse transforms (k_inv_y, k_mid stage C),
// wave-parallel j=16 tail in k_fwd_y (shfl_xor reduce), Xf stride 34 to kill
// stage-B bank conflicts.

#define TWO_PI_OVER_128 0.04908738521234052f

// ---------------- K0: t1/t2 = t_emb @ (k_real, k_imag) -> tbuf[which][b][i][2]
__global__ __launch_bounds__(128) void k_tproj(
    const float* __restrict__ temb, const float* __restrict__ k1r, const float* __restrict__ k1i,
    const float* __restrict__ k2r, const float* __restrict__ k2i, float* __restrict__ tbuf)
{
    int b = blockIdx.x, tid = threadIdx.x;
    __shared__ float ts[256];
    for (int d = tid; d < 256; d += 128) ts[d] = temb[b * 256 + d];
    __syncthreads();
    if (tid < 68) {
        int which = (tid >= 34) ? 1 : 0;
        int rem = tid - which * 34;
        int i = rem >> 1, part = rem & 1;
        const float* kp = which ? (part ? k2i : k2r) : (part ? k1i : k1r);
        float a0 = 0.f, a1 = 0.f, a2 = 0.f, a3 = 0.f;
        for (int d = 0; d < 256; d += 4) {
            a0 = fmaf(ts[d],     kp[(d)     * 17 + i], a0);
            a1 = fmaf(ts[d + 1], kp[(d + 1) * 17 + i], a1);
            a2 = fmaf(ts[d + 2], kp[(d + 2) * 17 + i], a2);
            a3 = fmaf(ts[d + 3], kp[(d + 3) * 17 + i], a3);
        }
        tbuf[((which * 32 + b) * 17 + i) * 2 + part] = (a0 + a1) + (a2 + a3);
    }
}

// ---------------- K1: y-axis DFT with y<->128-y folding. block = (b,x), 64 thr.
// Twiddles from LDS table cst[k] = (cos(2πk/128), -sin(2πk/128)).
// j=16 tail parallelized across all 8 jg groups (constant twiddle per lane,
// since 16*y mod 128 has period 8 in y) + shfl_xor tree reduce.
__global__ __launch_bounds__(64) void k_fwd_y(const float* __restrict__ x, float2* __restrict__ T1)
{
    int blk = blockIdx.x;
    int b = blk >> 7, xr = blk & 127;
    __shared__ float xs[128 * 32];
    __shared__ float2 cst[128];
    int tid = threadIdx.x;
    {
        float s0, c0; sincosf(TWO_PI_OVER_128 * (float)tid, &s0, &c0);
        cst[tid] = make_float2(c0, -s0);
        float s1, c1; sincosf(TWO_PI_OVER_128 * (float)(tid + 64), &s1, &c1);
        cst[tid + 64] = make_float2(c1, -s1);
    }
    const float4* xv = (const float4*)(x + ((size_t)blk << 12));
    float4* xs4 = (float4*)xs;
#pragma unroll
    for (int i = 0; i < 16; ++i) xs4[tid + (i << 6)] = xv[tid + (i << 6)];
    __syncthreads();
    for (int i = tid; i < 2016; i += 64) {
        int y = (i >> 5) + 1, c = i & 31;
        float a = xs[(y << 5) + c], q = xs[((128 - y) << 5) + c];
        xs[(y << 5) + c] = a + q;
        xs[((128 - y) << 5) + c] = a - q;
    }
    __syncthreads();
    int jg = tid >> 3, cg = tid & 7, c0 = cg << 2;
    float re[2][4] = {{0,0,0,0},{0,0,0,0}}, im[2][4] = {{0,0,0,0},{0,0,0,0}};
    int j0 = jg, j1 = jg + 8;
    int idx0 = 0, idx1 = 0;
    for (int y = 1; y <= 63; ++y) {
        idx0 = (idx0 + j0) & 127;
        idx1 = (idx1 + j1) & 127;
        float2 w0 = cst[idx0], w1 = cst[idx1];
        float4 s = *(const float4*)&xs[(y << 5) + c0];
        float4 d = *(const float4*)&xs[((128 - y) << 5) + c0];
        re[0][0] = fmaf(s.x, w0.x, re[0][0]);
        re[0][1] = fmaf(s.y, w0.x, re[0][1]);
        re[0][2] = fmaf(s.z, w0.x, re[0][2]);
        re[0][3] = fmaf(s.w, w0.x, re[0][3]);
        im[0][0] = fmaf(d.x, w0.y, im[0][0]);
        im[0][1] = fmaf(d.y, w0.y, im[0][1]);
        im[0][2] = fmaf(d.z, w0.y, im[0][2]);
        im[0][3] = fmaf(d.w, w0.y, im[0][3]);
        re[1][0] = fmaf(s.x, w1.x, re[1][0]);
        re[1][1] = fmaf(s.y, w1.x, re[1][1]);
        re[1][2] = fmaf(s.z, w1.x, re[1][2]);
        re[1][3] = fmaf(s.w, w1.x, re[1][3]);
        im[1][0] = fmaf(d.x, w1.y, im[1][0]);
        im[1][1] = fmaf(d.y, w1.y, im[1][1]);
        im[1][2] = fmaf(d.z, w1.y, im[1][2]);
        im[1][3] = fmaf(d.w, w1.y, im[1][3]);
    }
    const float s_ = 1.f / 16384.f;
    float x0[4], x64[4];
    *(float4*)x0  = *(const float4*)&xs[c0];
    *(float4*)x64 = *(const float4*)&xs[(64 << 5) + c0];
#pragma unroll
    for (int t = 0; t < 2; ++t) {
        int j = jg + t * 8;
        float sg = (j & 1) ? -1.f : 1.f;
        float2* p = T1 + (((size_t)(b * 17 + j) * 128 + xr) << 5) + c0;
        float4 v0 = make_float4((re[t][0] + x0[0] + sg * x64[0]) * s_, im[t][0] * s_,
                                (re[t][1] + x0[1] + sg * x64[1]) * s_, im[t][1] * s_);
        float4 v1 = make_float4((re[t][2] + x0[2] + sg * x64[2]) * s_, im[t][2] * s_,
                                (re[t][3] + x0[3] + sg * x64[3]) * s_, im[t][3] * s_);
        ((float4*)p)[0] = v0; ((float4*)p)[1] = v1;
    }
    // ---- j=16 tail: all 64 lanes. Each jg-group sums y ∈ {jg+1, jg+9, ...} (≤63);
    // twiddle (16*y)&127 = 16*(jg+1)&127 is constant per lane. Reduce over jg.
    {
        float re2[4] = {0,0,0,0}, im2[4] = {0,0,0,0};
        float2 w16 = cst[(16 * (jg + 1)) & 127];
        for (int y = jg + 1; y <= 63; y += 8) {
            float4 s = *(const float4*)&xs[(y << 5) + c0];
            float4 d = *(const float4*)&xs[((128 - y) << 5) + c0];
            re2[0] = fmaf(s.x, w16.x, re2[0]); re2[1] = fmaf(s.y, w16.x, re2[1]);
            re2[2] = fmaf(s.z, w16.x, re2[2]); re2[3] = fmaf(s.w, w16.x, re2[3]);
            im2[0] = fmaf(d.x, w16.y, im2[0]); im2[1] = fmaf(d.y, w16.y, im2[1]);
            im2[2] = fmaf(d.z, w16.y, im2[2]); im2[3] = fmaf(d.w, w16.y, im2[3]);
        }
#pragma unroll
        for (int t = 0; t < 4; ++t) {
            re2[t] += __shfl_xor(re2[t], 8);
            re2[t] += __shfl_xor(re2[t], 16);
            re2[t] += __shfl_xor(re2[t], 32);
            im2[t] += __shfl_xor(im2[t], 8);
            im2[t] += __shfl_xor(im2[t], 16);
            im2[t] += __shfl_xor(im2[t], 32);
        }
        if (jg == 0) {
            float2* p = T1 + (((size_t)(b * 17 + 16) * 128 + xr) << 5) + c0;
            float4 v0 = make_float4((re2[0] + x0[0] + x64[0]) * s_, im2[0] * s_,
                                    (re2[1] + x0[1] + x64[1]) * s_, im2[1] * s_);
            float4 v1 = make_float4((re2[2] + x0[2] + x64[2]) * s_, im2[2] * s_,
                                    (re2[3] + x0[3] + x64[3]) * s_, im2[3] * s_);
            ((float4*)p)[0] = v0; ((float4*)p)[1] = v1;
        }
    }
}

// ---------------- K2': fused x-DFT + mix + inverse-x. block=(b,j), 512 thr.
// Stage A: 18 balanced units, table twiddles, Xf stride 34 (bank-conflict-free).
// Stage B: float4 weight loads.
// Stage C: parity-fold quad-output (x, 64-x, 64+x, 128-x per unit).
#define XFS 34
__global__ __launch_bounds__(512) void k_mid_fused(
    const float2* __restrict__ T1, const float* __restrict__ w1r, const float* __restrict__ w1i,
    const float* __restrict__ w2r, const float* __restrict__ w2i,
    const float* __restrict__ tbuf, float2* __restrict__ U)
{
    int blk = blockIdx.x;
    int b = blk / 17, j = blk - b * 17;
    __shared__ float4 Ts4[2048];          // 32 KB tile; reused as Ys after stage A
    __shared__ float2 Xf[34 * XFS];       // stride 34: banks (4ii+2c)%32 distinct
    __shared__ float2 cst[128];           // (cos, sin) table
    int tid = threadIdx.x;
    const float4* s4 = (const float4*)(T1 + (size_t)blk * 4096);
    for (int i = tid; i < 2048; i += 512) Ts4[i] = s4[i];
    if (tid < 128) {
        float s, c; sincosf(TWO_PI_OVER_128 * (float)tid, &s, &c);
        cst[tid] = make_float2(c, s);
    }
    __syncthreads();
    // fold x<->128-x
    for (int i = tid; i < 1008; i += 512) {
        int xx = (i >> 4) + 1, cp = i & 15;
        float4 a = Ts4[(xx << 4) + cp], q = Ts4[((128 - xx) << 4) + cp];
        Ts4[(xx << 4) + cp] = make_float4(a.x + q.x, a.y + q.y, a.z + q.z, a.w + q.w);
        Ts4[((128 - xx) << 4) + cp] = make_float4(a.x - q.x, a.y - q.y, a.z - q.z, a.w - q.w);
    }
    __syncthreads();
    // ---- stage A: 18 units x 16 cp = 288 threads, balanced
    if (tid < 288) {
        int cp = tid & 15, u = tid >> 4;
        float4 t0 = Ts4[cp], t64 = Ts4[(64 << 4) + cp];
        if (u < 16) {
            int f = u + 1;
            int idx = 0;
            float P0=0,Q0=0,R0=0,T0=0,P1=0,Q1=0,R1=0,T1a=0;
            for (int xx = 1; xx <= 63; ++xx) {
                idx = (idx + f) & 127;
                float2 w = cst[idx];
                float4 S = Ts4[(xx << 4) + cp];
                float4 D = Ts4[((128 - xx) << 4) + cp];
                P0 = fmaf(S.x, w.x, P0); Q0 = fmaf(D.y, w.y, Q0);
                R0 = fmaf(S.y, w.x, R0); T0 = fmaf(D.x, w.y, T0);
                P1 = fmaf(S.z, w.x, P1); Q1 = fmaf(D.w, w.y, Q1);
                R1 = fmaf(S.w, w.x, R1); T1a = fmaf(D.z, w.y, T1a);
            }
            float sg = (f & 1) ? -1.f : 1.f;
            float b0r = t0.x + sg * t64.x, b0i = t0.y + sg * t64.y;
            float b1r = t0.z + sg * t64.z, b1i = t0.w + sg * t64.w;
            int ia = f, ib = 34 - f;
            Xf[ia * XFS + cp*2]   = make_float2(P0 + Q0 + b0r, R0 - T0 + b0i);
            Xf[ia * XFS + cp*2+1] = make_float2(P1 + Q1 + b1r, R1 - T1a + b1i);
            Xf[ib * XFS + cp*2]   = make_float2(P0 - Q0 + b0r, R0 + T0 + b0i);
            Xf[ib * XFS + cp*2+1] = make_float2(P1 - Q1 + b1r, R1 + T1a + b1i);
        } else if (u == 16) {                       // f=0 (ii=0)
            float A0=0,B0=0,A1=0,B1=0;
            for (int xx = 1; xx <= 63; ++xx) {
                float4 S = Ts4[(xx << 4) + cp];
                A0 += S.x; B0 += S.y; A1 += S.z; B1 += S.w;
            }
            Xf[cp*2]   = make_float2(A0 + t0.x + t64.x, B0 + t0.y + t64.y);
            Xf[cp*2+1] = make_float2(A1 + t0.z + t64.z, B1 + t0.w + t64.w);
        } else {                                    // u == 17: f=111 (ii=17)
            int idx = 0;
            float p0=0,q0=0,r0=0,s0=0,p1=0,q1=0,r1=0,s1=0;
            for (int xx = 1; xx <= 63; ++xx) {
                idx = (idx + 111) & 127;
                float2 w = cst[idx];
                float4 S = Ts4[(xx << 4) + cp];
                float4 D = Ts4[((128 - xx) << 4) + cp];
                p0 = fmaf(S.x, w.x, p0); q0 = fmaf(D.y, w.y, q0);
                r0 = fmaf(S.y, w.x, r0); s0 = fmaf(D.x, w.y, s0);
                p1 = fmaf(S.z, w.x, p1); q1 = fmaf(D.w, w.y, q1);
                r1 = fmaf(S.w, w.x, r1); s1 = fmaf(D.z, w.y, s1);
            }
            float c0r = t0.x - t64.x, c0i = t0.y - t64.y;
            float c1r = t0.z - t64.z, c1i = t0.w - t64.w;
            Xf[17*XFS + cp*2]   = make_float2(p0 + q0 + c0r, r0 - s0 + c0i);
            Xf[17*XFS + cp*2+1] = make_float2(p1 + q1 + c1r, r1 - s1 + c1i);
        }
    }
    __syncthreads();
    // ---- stage B: Ys[ii][o] = t * sum_c Xf[ii][c] * w[irow,j,c,o], float4 loads
    float2* Ys = (float2*)Ts4;
    if (tid < 272) {
        int oq = tid & 7, ii = tid >> 3;
        int o0 = oq << 2;
        int irow = (ii < 17) ? ii : ii - 17;
        const float* wr = ((ii < 17) ? w1r : w2r) + ((irow * 17 + j) << 10) + o0;
        const float* wi = ((ii < 17) ? w1i : w2i) + ((irow * 17 + j) << 10) + o0;
        float ar0=0,ai0=0,ar1=0,ai1=0,ar2=0,ai2=0,ar3=0,ai3=0;
#pragma unroll 4
        for (int c = 0; c < 32; ++c) {
            float2 xv = Xf[ii * XFS + c];
            float4 wre = *(const float4*)(wr + (c << 5));
            float4 wim = *(const float4*)(wi + (c << 5));
            ar0 = fmaf(xv.x, wre.x, ar0); ar0 = fmaf(-xv.y, wim.x, ar0);
            ai0 = fmaf(xv.x, wim.x, ai0); ai0 = fmaf( xv.y, wre.x, ai0);
            ar1 = fmaf(xv.x, wre.y, ar1); ar1 = fmaf(-xv.y, wim.y, ar1);
            ai1 = fmaf(xv.x, wim.y, ai1); ai1 = fmaf( xv.y, wre.y, ai1);
            ar2 = fmaf(xv.x, wre.z, ar2); ar2 = fmaf(-xv.y, wim.z, ar2);
            ai2 = fmaf(xv.x, wim.z, ai2); ai2 = fmaf( xv.y, wre.z, ai2);
            ar3 = fmaf(xv.x, wre.w, ar3); ar3 = fmaf(-xv.y, wim.w, ar3);
            ai3 = fmaf(xv.x, wim.w, ai3); ai3 = fmaf( xv.y, wre.w, ai3);
        }
        int which = (ii >= 17) ? 1 : 0;
        const float* tp = tbuf + ((which * 32 + b) * 17 + irow) * 2;
        float tr = tp[0], ti = tp[1];
        float2* yp = Ys + ii * 32 + o0;
        float4 y01 = make_float4(ar0 * tr - ai0 * ti, ar0 * ti + ai0 * tr,
                                 ar1 * tr - ai1 * ti, ar1 * ti + ai1 * tr);
        float4 y23 = make_float4(ar2 * tr - ai2 * ti, ar2 * ti + ai2 * tr,
                                 ar3 * tr - ai3 * ti, ar3 * ti + ai3 * tr);
        ((float4*)yp)[0] = y01;
        ((float4*)yp)[1] = y23;
    }
    __syncthreads();
    // ---- stage C: parity-fold quads (x, 64-x, 64+x, 128-x); specials x=0,64
    {
        int o = tid & 31, g = tid >> 5;              // g 0..15
        float yr[34], yi[34];
#pragma unroll
        for (int i = 0; i < 34; ++i) { float2 v = Ys[i * 32 + o]; yr[i] = v.x; yi[i] = v.y; }
        float2* Ub = U + ((size_t)b * 128 * 17 + j) * 32 + o;
        if (g == 0) {                                // x = 0
            float sr = 0.f, si = 0.f;
#pragma unroll
            for (int i = 0; i < 34; ++i) { sr += yr[i]; si += yi[i]; }
            Ub[0] = make_float2(sr, si);
        }
        if (g == 1) {                                // x = 64
            float sr = 0.f, si = 0.f;
#pragma unroll
            for (int i = 0; i < 34; ++i) {
                float sg2 = (i & 1) ? -1.f : 1.f;
                sr = fmaf(sg2, yr[i], sr); si = fmaf(sg2, yi[i], si);
            }
            Ub[(size_t)64 * 544] = make_float2(sr, si);
        }
        for (int k = 0; k < 2; ++k) {
            int x = 1 + g + (k << 4);                // x ∈ 1..32 (x=32 dup writes, same thread, consistent)
            float A1e=0,A1o=0,A2e=0,A2o=0,A3e=0,A3o=0,A4e=0,A4o=0;
            int idx = 0;
#pragma unroll
            for (int i = 0; i < 17; ++i) {
                float2 w = cst[idx];
                if (i & 1) {
                    A1o = fmaf(yr[i], w.x, A1o); A4o = fmaf(yr[i], w.y, A4o);
                    A3o = fmaf(yi[i], w.x, A3o); A2o = fmaf(yi[i], w.y, A2o);
                } else {
                    A1e = fmaf(yr[i], w.x, A1e); A4e = fmaf(yr[i], w.y, A4e);
                    A3e = fmaf(yi[i], w.x, A3e); A2e = fmaf(yi[i], w.y, A2e);
                }
                idx = (idx + x) & 127;
            }
            idx = (111 * x) & 127;
#pragma unroll
            for (int i = 17; i < 34; ++i) {
                float2 w = cst[idx];
                if (i & 1) {
                    A1o = fmaf(yr[i], w.x, A1o); A4o = fmaf(yr[i], w.y, A4o);
                    A3o = fmaf(yi[i], w.x, A3o); A2o = fmaf(yi[i], w.y, A2o);
                } else {
                    A1e = fmaf(yr[i], w.x, A1e); A4e = fmaf(yr[i], w.y, A4e);
                    A3e = fmaf(yi[i], w.x, A3e); A2e = fmaf(yi[i], w.y, A2e);
                }
                idx = (idx + x) & 127;
            }
            float A1 = A1e + A1o, A2 = A2e + A2o, A3 = A3e + A3o, A4 = A4e + A4o;
            float E1 = A1e - A1o, E2 = A2o - A2e, E3 = A3e - A3o, E4 = A4o - A4e;
            Ub[(size_t)x * 544]         = make_float2(A1 - A2, A3 + A4);
            Ub[(size_t)(128 - x) * 544] = make_float2(A1 + A2, A3 - A4);
            Ub[(size_t)(64 - x) * 544]  = make_float2(E1 - E2, E3 + E4);
            Ub[(size_t)(64 + x) * 544]  = make_float2(E1 + E2, E3 - E4);
        }
    }
}

// ---------------- Fallback K2/K3 (R3 versions, used if ws too small) ----------
__global__ __launch_bounds__(256) void k_fwd_x_mix(
    const float2* __restrict__ T1, const float* __restrict__ w1r, const float* __restrict__ w1i,
    const float* __restrict__ w2r, const float* __restrict__ w2i,
    const float* __restrict__ tbuf, float2* __restrict__ Y)
{
    int blk = blockIdx.x;
    int b = blk / 17, j = blk - b * 17;
    __shared__ float4 Ts4[2048];
    __shared__ float2 Xf[34 * 32];
    int tid = threadIdx.x;
    const float4* s4 = (const float4*)(T1 + (size_t)blk * 4096);
    for (int i = tid; i < 2048; i += 256) Ts4[i] = s4[i];
    __syncthreads();
    {
        int cp = tid & 15, g = tid >> 4;
        int il[3] = {g, g + 16, g + 32};
        float stc[3], sts[3];
#pragma unroll
        for (int t = 0; t < 3; ++t) {
            int i = il[t];
            int f = (i < 17) ? i : i + 94;
            float a = -TWO_PI_OVER_128 * (float)(f & 127);
            sincosf(a, &sts[t], &stc[t]);
        }
        float cr[3] = {1.f, 1.f, 1.f}, ci[3] = {0.f, 0.f, 0.f};
        float r0[3] = {0,0,0}, i0[3] = {0,0,0}, r1[3] = {0,0,0}, i1[3] = {0,0,0};
        const float4* Tc = Ts4 + cp;
#pragma unroll 2
        for (int xx = 0; xx < 128; ++xx) {
            float4 tv = Tc[xx << 4];
#pragma unroll
            for (int t = 0; t < 3; ++t) {
                r0[t] += tv.x * cr[t] - tv.y * ci[t];
                i0[t] += tv.x * ci[t] + tv.y * cr[t];
                r1[t] += tv.z * cr[t] - tv.w * ci[t];
                i1[t] += tv.z * ci[t] + tv.w * cr[t];
                float nr = cr[t] * stc[t] - ci[t] * sts[t];
                ci[t] = fmaf(cr[t], sts[t], ci[t] * stc[t]);
                cr[t] = nr;
            }
        }
#pragma unroll
        for (int t = 0; t < 3; ++t) {
            int i = il[t];
            if (i < 34) {
                Xf[i * 32 + cp * 2]     = make_float2(r0[t], i0[t]);
                Xf[i * 32 + cp * 2 + 1] = make_float2(r1[t], i1[t]);
            }
        }
    }
    __syncthreads();
    {
        int o = tid & 31, gi = tid >> 5;
#pragma unroll
        for (int t = 0; t < 5; ++t) {
            int ii = gi + (t << 3);
            if (ii < 34) {
                int irow = (ii < 17) ? ii : ii - 17;
                const float* wr = ((ii < 17) ? w1r : w2r) + ((irow * 17 + j) << 10) + o;
                const float* wi = ((ii < 17) ? w1i : w2i) + ((irow * 17 + j) << 10) + o;
                float ar = 0.f, ai = 0.f;
#pragma unroll 8
                for (int cc2 = 0; cc2 < 32; ++cc2) {
                    float2 xv = Xf[ii * 32 + cc2];
                    float wre = wr[cc2 << 5];
                    float wim = wi[cc2 << 5];
                    ar += xv.x * wre - xv.y * wim;
                    ai += xv.x * wim + xv.y * wre;
                }
                int which = (ii >= 17) ? 1 : 0;
                const float* tp = tbuf + ((which * 32 + b) * 17 + irow) * 2;
                float tr = tp[0], ti = tp[1];
                Y[(size_t)blk * (34 * 32) + ii * 32 + o] =
                    make_float2(ar * tr - ai * ti, ar * ti + ai * tr);
            }
        }
    }
}

__global__ __launch_bounds__(256) void k_inv_x(const float2* __restrict__ Y, float2* __restrict__ U)
{
    int blk = blockIdx.x;
    int b = blk / 17, j = blk - b * 17;
    __shared__ float2 Ys[34 * 32];
    __shared__ float ct[128], st[128];
    int tid = threadIdx.x;
    if (tid < 128) {
        float a = TWO_PI_OVER_128 * (float)tid;
        sincosf(a, &st[tid], &ct[tid]);
    }
    const float2* src = Y + (size_t)blk * (34 * 32);
    for (int i = tid; i < 34 * 32; i += 256) Ys[i] = src[i];
    __syncthreads();
    int o = tid & 31, g = tid >> 5;
    float yr[34], yi[34];
#pragma unroll
    for (int i = 0; i < 34; ++i) { float2 v = Ys[i * 32 + o]; yr[i] = v.x; yi[i] = v.y; }
    for (int xi = 0; xi < 16; ++xi) {
        int xr = (xi << 3) + g;
        float cx = ct[xr], sx = st[xr];
        float cr = 1.f, ci = 0.f, re = 0.f, im = 0.f;
#pragma unroll
        for (int i = 0; i < 17; ++i) {
            re += yr[i] * cr - yi[i] * ci;
            im += yr[i] * ci + yi[i] * cr;
            float nr = cr * cx - ci * sx;
            ci = fmaf(cr, sx, ci * cx);
            cr = nr;
        }
        int k2 = (111 * xr) & 127;
        cr = ct[k2]; ci = st[k2];
#pragma unroll
        for (int i = 17; i < 34; ++i) {
            re += yr[i] * cr - yi[i] * ci;
            im += yr[i] * ci + yi[i] * cr;
            float nr = cr * cx - ci * sx;
            ci = fmaf(cr, sx, ci * cx);
            cr = nr;
        }
        U[(((size_t)(b * 128 + xr)) * 17 + j) * 32 + o] = make_float2(re, im);
    }
}

// ---------------- K4: inverse y-axis c2r, parity-fold quad-output.
// out[y]     = base + (Ae+Ao) - (Be+Bo)
// out[128-y] = base + (Ae+Ao) + (Be+Bo)
// out[64-y]  = base + (Ae-Ao) + (Be-Bo)
// out[64+y]  = base + (Ae-Ao) - (Be-Bo)
// with A = Σ_j 2U.re_j cos(2πjy/128), B = Σ_j 2U.im_j sin(...), parity of j.
__global__ __launch_bounds__(128) void k_inv_y(const float2* __restrict__ U, float* __restrict__ out)
{
    int blk = blockIdx.x;
    __shared__ float2 Us[17 * 32];
    __shared__ float2 cst[128];
    int tid = threadIdx.x;
    {
        float s, c; sincosf(TWO_PI_OVER_128 * (float)tid, &s, &c);
        cst[tid] = make_float2(c, s);
    }
    const float4* src4 = (const float4*)(U + (size_t)blk * 544);
    float4* Us4 = (float4*)Us;
    for (int i = tid; i < 272; i += 128) Us4[i] = src4[i];
    __syncthreads();
    int cg = tid & 15, yg = tid >> 4, c0 = cg << 1;
    float base0, base1;
    {
        float4 v = *(const float4*)&Us[c0];
        base0 = v.x; base1 = v.z;
    }
    float urr[16][2], uii[16][2];
#pragma unroll
    for (int jj = 1; jj <= 16; ++jj) {
        float4 v = *(const float4*)&Us[jj * 32 + c0];
        urr[jj-1][0] = 2.f * v.x; uii[jj-1][0] = 2.f * v.y;
        urr[jj-1][1] = 2.f * v.z; uii[jj-1][1] = 2.f * v.w;
    }
    float* op = out + ((size_t)blk << 12);
    for (int k = 0; k < 4; ++k) {
        int y = 1 + yg + (k << 3);                   // y ∈ 1..32 (y=32: dup writes, same thread)
        float Ae0=0,Ao0=0,Be0=0,Bo0=0,Ae1=0,Ao1=0,Be1=0,Bo1=0;
        int idx = y;
#pragma unroll
        for (int jj = 0; jj < 16; ++jj) {            // j = jj+1; parity of j
            float2 w = cst[idx];
            if (jj & 1) {                            // j even
                Ae0 = fmaf(urr[jj][0], w.x, Ae0); Be0 = fmaf(uii[jj][0], w.y, Be0);
                Ae1 = fmaf(urr[jj][1], w.x, Ae1); Be1 = fmaf(uii[jj][1], w.y, Be1);
            } else {                                 // j odd
                Ao0 = fmaf(urr[jj][0], w.x, Ao0); Bo0 = fmaf(uii[jj][0], w.y, Bo0);
                Ao1 = fmaf(urr[jj][1], w.x, Ao1); Bo1 = fmaf(uii[jj][1], w.y, Bo1);
            }
            idx = (idx + y) & 127;
        }
        float s0 = Ae0 + Ao0, d0 = Be0 + Bo0, e0 = Ae0 - Ao0, f0 = Be0 - Bo0;
        float s1 = Ae1 + Ao1, d1 = Be1 + Bo1, e1 = Ae1 - Ao1, f1 = Be1 - Bo1;
        *(float2*)&op[(y << 5) + c0]         = make_float2(base0 + s0 - d0, base1 + s1 - d1);
        *(float2*)&op[((128 - y) << 5) + c0] = make_float2(base0 + s0 + d0, base1 + s1 + d1);
        *(float2*)&op[((64 - y) << 5) + c0]  = make_float2(base0 + e0 + f0, base1 + e1 + f1);
        *(float2*)&op[((64 + y) << 5) + c0]  = make_float2(base0 + e0 - f0, base1 + e1 - f1);
    }
    if (yg == 0) {                                   // out[0], out[64]
        float s0 = 0.f, s1 = 0.f, a0 = 0.f, a1 = 0.f;
#pragma unroll
        for (int jj = 0; jj < 16; ++jj) {
            s0 += urr[jj][0]; s1 += urr[jj][1];
            float sg = (jj & 1) ? 1.f : -1.f;        // (-1)^j, j = jj+1
            a0 = fmaf(sg, urr[jj][0], a0); a1 = fmaf(sg, urr[jj][1], a1);
        }
        *(float2*)&op[c0]             = make_float2(base0 + s0, base1 + s1);
        *(float2*)&op[(64 << 5) + c0] = make_float2(base0 + a0, base1 + a1);
    }
}

extern "C" void kernel_launch(void* const* d_in, const int* in_sizes, int n_in,
                              void* d_out, int out_size, void* d_ws, size_t ws_size,
                              hipStream_t stream)
{
    const float* x    = (const float*)d_in[0];
    const float* temb = (const float*)d_in[1];
    const float* w1r  = (const float*)d_in[2];
    const float* w1i  = (const float*)d_in[3];
    const float* w2r  = (const float*)d_in[4];
    const float* w2i  = (const float*)d_in[5];
    const float* k1r  = (const float*)d_in[6];
    const float* k1i  = (const float*)d_in[7];
    const float* k2r  = (const float*)d_in[8];
    const float* k2i  = (const float*)d_in[9];
    float* out = (float*)d_out;

    char* ws = (char*)d_ws;
    const size_t T1_BYTES = 17825792;                  // 32*17*128*32 float2
    const size_t NEED_FUSED = 2 * T1_BYTES + 8704;     // T1 + U + tbuf

    if (ws_size >= NEED_FUSED) {
        float2* T1 = (float2*)ws;
        float2* U  = (float2*)(ws + T1_BYTES);
        float*  tb = (float*)(ws + 2 * T1_BYTES);
        k_tproj    <<<32,   128, 0, stream>>>(temb, k1r, k1i, k2r, k2i, tb);
        k_fwd_y    <<<4096, 64,  0, stream>>>(x, T1);
        k_mid_fused<<<544,  512, 0, stream>>>(T1, w1r, w1i, w2r, w2i, tb, U);
        k_inv_y    <<<4096, 128, 0, stream>>>(U, out);
    } else {
        float2* T1 = (float2*)ws;
        float2* Yb = (float2*)(ws + T1_BYTES);
        float*  tb = (float*)(ws + T1_BYTES + 4734976);
        float2* U  = T1;
        k_tproj    <<<32,   128, 0, stream>>>(temb, k1r, k1i, k2r, k2i, tb);
        k_fwd_y    <<<4096, 64,  0, stream>>>(x, T1);
        k_fwd_x_mix<<<544,  256, 0, stream>>>(T1, w1r, w1i, w2r, w2i, tb, Yb);
        k_inv_x    <<<544,  256, 0, stream>>>(Yb, U);
        k_inv_y    <<<4096, 128, 0, stream>>>(U, out);
    }
}

// Round 5
// 182.745 us; speedup vs baseline: 1.1657x; 1.0265x over previous
//
#include <hip/hip_runtime.h>
#include <stdint.h>

// SpectralFreqTimeConv2D: B=32, N=128, C=32, M=17. Truncated-DFT factorization.
// R7: full parity quad-fold in k_fwd_y and k_mid stage A (63->31 iter main
// loops, single-pass SE/SO/DE/DO fold), t-projection fused into k_mid's idle
// waves (k_tproj launch dropped on fused path).

#define TWO_PI_OVER_128 0.04908738521234052f

__device__ __forceinline__ float4 f4add(float4 a, float4 b) {
    return make_float4(a.x + b.x, a.y + b.y, a.z + b.z, a.w + b.w);
}
__device__ __forceinline__ float4 f4sub(float4 a, float4 b) {
    return make_float4(a.x - b.x, a.y - b.y, a.z - b.z, a.w - b.w);
}

// ---------------- K0: t1/t2 = t_emb @ (k_real, k_imag) -> tbuf (fallback path only)
__global__ __launch_bounds__(128) void k_tproj(
    const float* __restrict__ temb, const float* __restrict__ k1r, const float* __restrict__ k1i,
    const float* __restrict__ k2r, const float* __restrict__ k2i, float* __restrict__ tbuf)
{
    int b = blockIdx.x, tid = threadIdx.x;
    __shared__ float ts[256];
    for (int d = tid; d < 256; d += 128) ts[d] = temb[b * 256 + d];
    __syncthreads();
    if (tid < 68) {
        int which = (tid >= 34) ? 1 : 0;
        int rem = tid - which * 34;
        int i = rem >> 1, part = rem & 1;
        const float* kp = which ? (part ? k2i : k2r) : (part ? k1i : k1r);
        float a0 = 0.f, a1 = 0.f, a2 = 0.f, a3 = 0.f;
        for (int d = 0; d < 256; d += 4) {
            a0 = fmaf(ts[d],     kp[(d)     * 17 + i], a0);
            a1 = fmaf(ts[d + 1], kp[(d + 1) * 17 + i], a1);
            a2 = fmaf(ts[d + 2], kp[(d + 2) * 17 + i], a2);
            a3 = fmaf(ts[d + 3], kp[(d + 3) * 17 + i], a3);
        }
        tbuf[((which * 32 + b) * 17 + i) * 2 + part] = (a0 + a1) + (a2 + a3);
    }
}

// ---------------- K1: y-axis DFT, quad fold (y | 64-y | 64+y | 128-y).
// Rows after fold: y=1..31 -> SE, 64-y -> SO, 128-y -> DE, 64+y -> DO,
// row 32 -> S32, row 96 -> D32, rows 0/64 untouched.
// re[j] = sum_{y=1..31} cos(t_jy) * SP_y + x0 + (-1)^j x64 + S32*cos(pi j/2)
// im[j] = sum_{y=1..31} (-sin(t_jy)) * DP_y + D32*(-sin(pi j/2))
// where parity P of j selects SE/DE (even) or SO/DO (odd).
__global__ __launch_bounds__(64) void k_fwd_y(const float* __restrict__ x, float2* __restrict__ T1)
{
    int blk = blockIdx.x;
    int b = blk >> 7, xr = blk & 127;
    __shared__ float xs[128 * 32];
    __shared__ float2 cst[128];
    int tid = threadIdx.x;
    {
        float s0, c0; sincosf(TWO_PI_OVER_128 * (float)tid, &s0, &c0);
        cst[tid] = make_float2(c0, -s0);
        float s1, c1; sincosf(TWO_PI_OVER_128 * (float)(tid + 64), &s1, &c1);
        cst[tid + 64] = make_float2(c1, -s1);
    }
    const float4* xv = (const float4*)(x + ((size_t)blk << 12));
    float4* xs4 = (float4*)xs;
#pragma unroll
    for (int i = 0; i < 16; ++i) xs4[tid + (i << 6)] = xv[tid + (i << 6)];
    __syncthreads();
    // single-pass quad fold (1024 scalar units: 992 quads + 32 for y=32 pair)
    for (int i = tid; i < 1024; i += 64) {
        int c = i & 31, t = i >> 5;
        if (t < 31) {
            int y = t + 1;
            float a  = xs[(y << 5) + c],        bb = xs[((64 - y) << 5) + c];
            float cc = xs[((64 + y) << 5) + c], d  = xs[((128 - y) << 5) + c];
            float Sy = a + d, Dy = a - d, Sm = bb + cc, Dm = bb - cc;
            xs[(y << 5) + c]         = Sy + Sm;   // SE
            xs[((64 - y) << 5) + c]  = Sy - Sm;   // SO
            xs[((128 - y) << 5) + c] = Dy - Dm;   // DE
            xs[((64 + y) << 5) + c]  = Dy + Dm;   // DO
        } else {
            float a = xs[(32 << 5) + c], q = xs[(96 << 5) + c];
            xs[(32 << 5) + c] = a + q;            // S32
            xs[(96 << 5) + c] = a - q;            // D32
        }
    }
    __syncthreads();
    int jg = tid >> 3, cg = tid & 7, c0 = cg << 2;
    int p = jg & 1;
    float re[2][4] = {{0,0,0,0},{0,0,0,0}}, im[2][4] = {{0,0,0,0},{0,0,0,0}};
    int j0 = jg, j1 = jg + 8;
    int idx0 = 0, idx1 = 0;
    for (int y = 1; y <= 31; ++y) {
        idx0 = (idx0 + j0) & 127;
        idx1 = (idx1 + j1) & 127;
        float2 w0 = cst[idx0], w1 = cst[idx1];
        int sr = p ? (64 - y) : y;
        int dr = p ? (64 + y) : (128 - y);
        float4 s = *(const float4*)&xs[(sr << 5) + c0];
        float4 d = *(const float4*)&xs[(dr << 5) + c0];
        re[0][0] = fmaf(s.x, w0.x, re[0][0]);
        re[0][1] = fmaf(s.y, w0.x, re[0][1]);
        re[0][2] = fmaf(s.z, w0.x, re[0][2]);
        re[0][3] = fmaf(s.w, w0.x, re[0][3]);
        im[0][0] = fmaf(d.x, w0.y, im[0][0]);
        im[0][1] = fmaf(d.y, w0.y, im[0][1]);
        im[0][2] = fmaf(d.z, w0.y, im[0][2]);
        im[0][3] = fmaf(d.w, w0.y, im[0][3]);
        re[1][0] = fmaf(s.x, w1.x, re[1][0]);
        re[1][1] = fmaf(s.y, w1.x, re[1][1]);
        re[1][2] = fmaf(s.z, w1.x, re[1][2]);
        re[1][3] = fmaf(s.w, w1.x, re[1][3]);
        im[1][0] = fmaf(d.x, w1.y, im[1][0]);
        im[1][1] = fmaf(d.y, w1.y, im[1][1]);
        im[1][2] = fmaf(d.z, w1.y, im[1][2]);
        im[1][3] = fmaf(d.w, w1.y, im[1][3]);
    }
    const float s_ = 1.f / 16384.f;
    float x0[4], x64[4], S32v[4], D32v[4];
    *(float4*)x0   = *(const float4*)&xs[c0];
    *(float4*)x64  = *(const float4*)&xs[(64 << 5) + c0];
    *(float4*)S32v = *(const float4*)&xs[(32 << 5) + c0];
    *(float4*)D32v = *(const float4*)&xs[(96 << 5) + c0];
    float2 w32 = cst[(j0 << 5) & 127];            // same for j0 and j1 (j1=j0+8)
    float sg = p ? -1.f : 1.f;
#pragma unroll
    for (int t = 0; t < 2; ++t) {
        int j = jg + t * 8;
        float2* pp = T1 + (((size_t)(b * 17 + j) * 128 + xr) << 5) + c0;
        float4 v0 = make_float4((re[t][0] + x0[0] + sg * x64[0] + S32v[0] * w32.x) * s_,
                                (im[t][0] + D32v[0] * w32.y) * s_,
                                (re[t][1] + x0[1] + sg * x64[1] + S32v[1] * w32.x) * s_,
                                (im[t][1] + D32v[1] * w32.y) * s_);
        float4 v1 = make_float4((re[t][2] + x0[2] + sg * x64[2] + S32v[2] * w32.x) * s_,
                                (im[t][2] + D32v[2] * w32.y) * s_,
                                (re[t][3] + x0[3] + sg * x64[3] + S32v[3] * w32.x) * s_,
                                (im[t][3] + D32v[3] * w32.y) * s_);
        ((float4*)pp)[0] = v0; ((float4*)pp)[1] = v1;
    }
    // ---- j=16 tail (even parity): SE/DE rows, y=1..31 split over jg groups.
    // Twiddle (16*y)&127 is constant per lane (y steps by 8 -> +128 == 0).
    {
        float re2[4] = {0,0,0,0}, im2[4] = {0,0,0,0};
        float2 w16 = cst[(16 * (jg + 1)) & 127];
        for (int y = jg + 1; y <= 31; y += 8) {
            float4 s = *(const float4*)&xs[(y << 5) + c0];
            float4 d = *(const float4*)&xs[((128 - y) << 5) + c0];
            re2[0] = fmaf(s.x, w16.x, re2[0]); re2[1] = fmaf(s.y, w16.x, re2[1]);
            re2[2] = fmaf(s.z, w16.x, re2[2]); re2[3] = fmaf(s.w, w16.x, re2[3]);
            im2[0] = fmaf(d.x, w16.y, im2[0]); im2[1] = fmaf(d.y, w16.y, im2[1]);
            im2[2] = fmaf(d.z, w16.y, im2[2]); im2[3] = fmaf(d.w, w16.y, im2[3]);
        }
#pragma unroll
        for (int t = 0; t < 4; ++t) {
            re2[t] += __shfl_xor(re2[t], 8);
            re2[t] += __shfl_xor(re2[t], 16);
            re2[t] += __shfl_xor(re2[t], 32);
            im2[t] += __shfl_xor(im2[t], 8);
            im2[t] += __shfl_xor(im2[t], 16);
            im2[t] += __shfl_xor(im2[t], 32);
        }
        if (jg == 0) {                            // j=16: cos(8pi)=1, sin=0
            float2* pp = T1 + (((size_t)(b * 17 + 16) * 128 + xr) << 5) + c0;
            float4 v0 = make_float4((re2[0] + x0[0] + x64[0] + S32v[0]) * s_, im2[0] * s_,
                                    (re2[1] + x0[1] + x64[1] + S32v[1]) * s_, im2[1] * s_);
            float4 v1 = make_float4((re2[2] + x0[2] + x64[2] + S32v[2]) * s_, im2[2] * s_,
                                    (re2[3] + x0[3] + x64[3] + S32v[3]) * s_, im2[3] * s_);
            ((float4*)pp)[0] = v0; ((float4*)pp)[1] = v1;
        }
    }
}

// ---------------- K2': fused x-DFT + mix + inverse-x + t-projection. 512 thr.
// Stage A: 18 generic units, quad-folded 31-iter loops; threads 320-387
// concurrently compute the 68 t-projection dots (replaces k_tproj).
// Stage B: float4 weight loads, t from LDS.
// Stage C: parity-fold quad-output (unchanged from R6).
#define XFS 34
__global__ __launch_bounds__(512) void k_mid_fused(
    const float2* __restrict__ T1, const float* __restrict__ w1r, const float* __restrict__ w1i,
    const float* __restrict__ w2r, const float* __restrict__ w2i,
    const float* __restrict__ temb, const float* __restrict__ k1r, const float* __restrict__ k1i,
    const float* __restrict__ k2r, const float* __restrict__ k2i, float2* __restrict__ U)
{
    int blk = blockIdx.x;
    int b = blk / 17, j = blk - b * 17;
    __shared__ float4 Ts4[2048];          // 32 KB tile; reused as Ys after stage A
    __shared__ float2 Xf[34 * XFS];       // stride 34 (bank-conflict-free)
    __shared__ float2 cst[128];           // (cos, sin) table
    __shared__ float tl[68];              // t1/t2 per (which, i, part)
    int tid = threadIdx.x;
    const float4* s4 = (const float4*)(T1 + (size_t)blk * 4096);
    for (int i = tid; i < 2048; i += 512) Ts4[i] = s4[i];
    if (tid < 128) {
        float s, c; sincosf(TWO_PI_OVER_128 * (float)tid, &s, &c);
        cst[tid] = make_float2(c, s);
    }
    __syncthreads();
    // single-pass quad fold: 512 float4 units (496 quads + 16 for x=32 pair)
    {
        int t = tid >> 4, cp = tid & 15;
        if (t < 31) {
            int y = t + 1;
            float4 a  = Ts4[(y << 4) + cp],        bb = Ts4[((64 - y) << 4) + cp];
            float4 cc = Ts4[((64 + y) << 4) + cp], d  = Ts4[((128 - y) << 4) + cp];
            float4 Sy = f4add(a, d), Dy = f4sub(a, d);
            float4 Sm = f4add(bb, cc), Dm = f4sub(bb, cc);
            Ts4[(y << 4) + cp]         = f4add(Sy, Sm);   // SE
            Ts4[((64 - y) << 4) + cp]  = f4sub(Sy, Sm);   // SO
            Ts4[((128 - y) << 4) + cp] = f4sub(Dy, Dm);   // DE
            Ts4[((64 + y) << 4) + cp]  = f4add(Dy, Dm);   // DO
        } else {
            float4 a = Ts4[(32 << 4) + cp], q = Ts4[(96 << 4) + cp];
            Ts4[(32 << 4) + cp] = f4add(a, q);            // S32
            Ts4[(96 << 4) + cp] = f4sub(a, q);            // D32
        }
    }
    __syncthreads();
    // ---- stage A: 18 generic units x 16 cp; t-dots on threads 320..387
    if (tid < 288) {
        int cp = tid & 15, u = tid >> 4;
        int f = (u < 16) ? (u + 1) : ((u == 16) ? 0 : 111);
        int p = f & 1;
        float4 t0 = Ts4[cp], t64 = Ts4[(64 << 4) + cp];
        float P0=0,Q0=0,R0=0,T0=0,P1=0,Q1=0,R1=0,T1a=0;
        int idx = 0;
        for (int xx = 1; xx <= 31; ++xx) {
            idx = (idx + f) & 127;
            float2 w = cst[idx];
            float4 S = Ts4[((p ? (64 - xx) : xx) << 4) + cp];
            float4 D = Ts4[((p ? (64 + xx) : (128 - xx)) << 4) + cp];
            P0 = fmaf(S.x, w.x, P0); Q0 = fmaf(D.y, w.y, Q0);
            R0 = fmaf(S.y, w.x, R0); T0 = fmaf(D.x, w.y, T0);
            P1 = fmaf(S.z, w.x, P1); Q1 = fmaf(D.w, w.y, Q1);
            R1 = fmaf(S.w, w.x, R1); T1a = fmaf(D.z, w.y, T1a);
        }
        {   // boundary x=32: S32 -> cos terms, D32 -> sin terms
            float2 w32 = cst[(f << 5) & 127];
            float4 S32 = Ts4[(32 << 4) + cp], D32 = Ts4[(96 << 4) + cp];
            P0 = fmaf(S32.x, w32.x, P0); Q0 = fmaf(D32.y, w32.y, Q0);
            R0 = fmaf(S32.y, w32.x, R0); T0 = fmaf(D32.x, w32.y, T0);
            P1 = fmaf(S32.z, w32.x, P1); Q1 = fmaf(D32.w, w32.y, Q1);
            R1 = fmaf(S32.w, w32.x, R1); T1a = fmaf(D32.z, w32.y, T1a);
        }
        float sg = p ? -1.f : 1.f;
        float b0r = t0.x + sg * t64.x, b0i = t0.y + sg * t64.y;
        float b1r = t0.z + sg * t64.z, b1i = t0.w + sg * t64.w;
        int ia = (u == 16) ? 0 : ((u == 17) ? 17 : f);
        Xf[ia * XFS + cp*2]   = make_float2(P0 + Q0 + b0r, R0 - T0 + b0i);
        Xf[ia * XFS + cp*2+1] = make_float2(P1 + Q1 + b1r, R1 - T1a + b1i);
        if (u < 16) {
            int ib = 34 - f;
            Xf[ib * XFS + cp*2]   = make_float2(P0 - Q0 + b0r, R0 + T0 + b0i);
            Xf[ib * XFS + cp*2+1] = make_float2(P1 - Q1 + b1r, R1 + T1a + b1i);
        }
    } else if (tid >= 320 && tid < 388) {
        int r = tid - 320;
        int which = (r >= 34) ? 1 : 0;
        int rem = r - which * 34;
        int i = rem >> 1, part = rem & 1;
        const float* kp = which ? (part ? k2i : k2r) : (part ? k1i : k1r);
        const float* tb = temb + b * 256;
        float a0 = 0.f, a1 = 0.f, a2 = 0.f, a3 = 0.f;
        for (int d = 0; d < 256; d += 4) {
            a0 = fmaf(tb[d],     kp[(d)     * 17 + i], a0);
            a1 = fmaf(tb[d + 1], kp[(d + 1) * 17 + i], a1);
            a2 = fmaf(tb[d + 2], kp[(d + 2) * 17 + i], a2);
            a3 = fmaf(tb[d + 3], kp[(d + 3) * 17 + i], a3);
        }
        tl[which * 34 + (i << 1) + part] = (a0 + a1) + (a2 + a3);
    }
    __syncthreads();
    // ---- stage B: Ys[ii][o] = t * sum_c Xf[ii][c] * w[irow,j,c,o], float4 loads
    float2* Ys = (float2*)Ts4;
    if (tid < 272) {
        int oq = tid & 7, ii = tid >> 3;
        int o0 = oq << 2;
        int irow = (ii < 17) ? ii : ii - 17;
        const float* wr = ((ii < 17) ? w1r : w2r) + ((irow * 17 + j) << 10) + o0;
        const float* wi = ((ii < 17) ? w1i : w2i) + ((irow * 17 + j) << 10) + o0;
        float ar0=0,ai0=0,ar1=0,ai1=0,ar2=0,ai2=0,ar3=0,ai3=0;
#pragma unroll 4
        for (int c = 0; c < 32; ++c) {
            float2 xv = Xf[ii * XFS + c];
            float4 wre = *(const float4*)(wr + (c << 5));
            float4 wim = *(const float4*)(wi + (c << 5));
            ar0 = fmaf(xv.x, wre.x, ar0); ar0 = fmaf(-xv.y, wim.x, ar0);
            ai0 = fmaf(xv.x, wim.x, ai0); ai0 = fmaf( xv.y, wre.x, ai0);
            ar1 = fmaf(xv.x, wre.y, ar1); ar1 = fmaf(-xv.y, wim.y, ar1);
            ai1 = fmaf(xv.x, wim.y, ai1); ai1 = fmaf( xv.y, wre.y, ai1);
            ar2 = fmaf(xv.x, wre.z, ar2); ar2 = fmaf(-xv.y, wim.z, ar2);
            ai2 = fmaf(xv.x, wim.z, ai2); ai2 = fmaf( xv.y, wre.z, ai2);
            ar3 = fmaf(xv.x, wre.w, ar3); ar3 = fmaf(-xv.y, wim.w, ar3);
            ai3 = fmaf(xv.x, wim.w, ai3); ai3 = fmaf( xv.y, wre.w, ai3);
        }
        int which = (ii >= 17) ? 1 : 0;
        float tr = tl[which * 34 + (irow << 1)], ti = tl[which * 34 + (irow << 1) + 1];
        float2* yp = Ys + ii * 32 + o0;
        float4 y01 = make_float4(ar0 * tr - ai0 * ti, ar0 * ti + ai0 * tr,
                                 ar1 * tr - ai1 * ti, ar1 * ti + ai1 * tr);
        float4 y23 = make_float4(ar2 * tr - ai2 * ti, ar2 * ti + ai2 * tr,
                                 ar3 * tr - ai3 * ti, ar3 * ti + ai3 * tr);
        ((float4*)yp)[0] = y01;
        ((float4*)yp)[1] = y23;
    }
    __syncthreads();
    // ---- stage C: parity-fold quads (x, 64-x, 64+x, 128-x); specials x=0,64
    {
        int o = tid & 31, g = tid >> 5;              // g 0..15
        float yr[34], yi[34];
#pragma unroll
        for (int i = 0; i < 34; ++i) { float2 v = Ys[i * 32 + o]; yr[i] = v.x; yi[i] = v.y; }
        float2* Ub = U + ((size_t)b * 128 * 17 + j) * 32 + o;
        if (g == 0) {                                // x = 0
            float sr = 0.f, si = 0.f;
#pragma unroll
            for (int i = 0; i < 34; ++i) { sr += yr[i]; si += yi[i]; }
            Ub[0] = make_float2(sr, si);
        }
        if (g == 1) {                                // x = 64
            float sr = 0.f, si = 0.f;
#pragma unroll
            for (int i = 0; i < 34; ++i) {
                float sg2 = (i & 1) ? -1.f : 1.f;
                sr = fmaf(sg2, yr[i], sr); si = fmaf(sg2, yi[i], si);
            }
            Ub[(size_t)64 * 544] = make_float2(sr, si);
        }
        for (int k = 0; k < 2; ++k) {
            int x = 1 + g + (k << 4);                // x in 1..32 (x=32 dup, same thread)
            float A1e=0,A1o=0,A2e=0,A2o=0,A3e=0,A3o=0,A4e=0,A4o=0;
            int idx = 0;
#pragma unroll
            for (int i = 0; i < 17; ++i) {
                float2 w = cst[idx];
                if (i & 1) {
                    A1o = fmaf(yr[i], w.x, A1o); A4o = fmaf(yr[i], w.y, A4o);
                    A3o = fmaf(yi[i], w.x, A3o); A2o = fmaf(yi[i], w.y, A2o);
                } else {
                    A1e = fmaf(yr[i], w.x, A1e); A4e = fmaf(yr[i], w.y, A4e);
                    A3e = fmaf(yi[i], w.x, A3e); A2e = fmaf(yi[i], w.y, A2e);
                }
                idx = (idx + x) & 127;
            }
            idx = (111 * x) & 127;
#pragma unroll
            for (int i = 17; i < 34; ++i) {
                float2 w = cst[idx];
                if (i & 1) {
                    A1o = fmaf(yr[i], w.x, A1o); A4o = fmaf(yr[i], w.y, A4o);
                    A3o = fmaf(yi[i], w.x, A3o); A2o = fmaf(yi[i], w.y, A2o);
                } else {
                    A1e = fmaf(yr[i], w.x, A1e); A4e = fmaf(yr[i], w.y, A4e);
                    A3e = fmaf(yi[i], w.x, A3e); A2e = fmaf(yi[i], w.y, A2e);
                }
                idx = (idx + x) & 127;
            }
            float A1 = A1e + A1o, A2 = A2e + A2o, A3 = A3e + A3o, A4 = A4e + A4o;
            float E1 = A1e - A1o, E2 = A2o - A2e, E3 = A3e - A3o, E4 = A4o - A4e;
            Ub[(size_t)x * 544]         = make_float2(A1 - A2, A3 + A4);
            Ub[(size_t)(128 - x) * 544] = make_float2(A1 + A2, A3 - A4);
            Ub[(size_t)(64 - x) * 544]  = make_float2(E1 - E2, E3 + E4);
            Ub[(size_t)(64 + x) * 544]  = make_float2(E1 + E2, E3 - E4);
        }
    }
}

// ---------------- Fallback K2/K3 (R3 versions, used if ws too small) ----------
__global__ __launch_bounds__(256) void k_fwd_x_mix(
    const float2* __restrict__ T1, const float* __restrict__ w1r, const float* __restrict__ w1i,
    const float* __restrict__ w2r, const float* __restrict__ w2i,
    const float* __restrict__ tbuf, float2* __restrict__ Y)
{
    int blk = blockIdx.x;
    int b = blk / 17, j = blk - b * 17;
    __shared__ float4 Ts4[2048];
    __shared__ float2 Xf[34 * 32];
    int tid = threadIdx.x;
    const float4* s4 = (const float4*)(T1 + (size_t)blk * 4096);
    for (int i = tid; i < 2048; i += 256) Ts4[i] = s4[i];
    __syncthreads();
    {
        int cp = tid & 15, g = tid >> 4;
        int il[3] = {g, g + 16, g + 32};
        float stc[3], sts[3];
#pragma unroll
        for (int t = 0; t < 3; ++t) {
            int i = il[t];
            int f = (i < 17) ? i : i + 94;
            float a = -TWO_PI_OVER_128 * (float)(f & 127);
            sincosf(a, &sts[t], &stc[t]);
        }
        float cr[3] = {1.f, 1.f, 1.f}, ci[3] = {0.f, 0.f, 0.f};
        float r0[3] = {0,0,0}, i0[3] = {0,0,0}, r1[3] = {0,0,0}, i1[3] = {0,0,0};
        const float4* Tc = Ts4 + cp;
#pragma unroll 2
        for (int xx = 0; xx < 128; ++xx) {
            float4 tv = Tc[xx << 4];
#pragma unroll
            for (int t = 0; t < 3; ++t) {
                r0[t] += tv.x * cr[t] - tv.y * ci[t];
                i0[t] += tv.x * ci[t] + tv.y * cr[t];
                r1[t] += tv.z * cr[t] - tv.w * ci[t];
                i1[t] += tv.z * ci[t] + tv.w * cr[t];
                float nr = cr[t] * stc[t] - ci[t] * sts[t];
                ci[t] = fmaf(cr[t], sts[t], ci[t] * stc[t]);
                cr[t] = nr;
            }
        }
#pragma unroll
        for (int t = 0; t < 3; ++t) {
            int i = il[t];
            if (i < 34) {
                Xf[i * 32 + cp * 2]     = make_float2(r0[t], i0[t]);
                Xf[i * 32 + cp * 2 + 1] = make_float2(r1[t], i1[t]);
            }
        }
    }
    __syncthreads();
    {
        int o = tid & 31, gi = tid >> 5;
#pragma unroll
        for (int t = 0; t < 5; ++t) {
            int ii = gi + (t << 3);
            if (ii < 34) {
                int irow = (ii < 17) ? ii : ii - 17;
                const float* wr = ((ii < 17) ? w1r : w2r) + ((irow * 17 + j) << 10) + o;
                const float* wi = ((ii < 17) ? w1i : w2i) + ((irow * 17 + j) << 10) + o;
                float ar = 0.f, ai = 0.f;
#pragma unroll 8
                for (int cc2 = 0; cc2 < 32; ++cc2) {
                    float2 xv = Xf[ii * 32 + cc2];
                    float wre = wr[cc2 << 5];
                    float wim = wi[cc2 << 5];
                    ar += xv.x * wre - xv.y * wim;
                    ai += xv.x * wim + xv.y * wre;
                }
                int which = (ii >= 17) ? 1 : 0;
                const float* tp = tbuf + ((which * 32 + b) * 17 + irow) * 2;
                float tr = tp[0], ti = tp[1];
                Y[(size_t)blk * (34 * 32) + ii * 32 + o] =
                    make_float2(ar * tr - ai * ti, ar * ti + ai * tr);
            }
        }
    }
}

__global__ __launch_bounds__(256) void k_inv_x(const float2* __restrict__ Y, float2* __restrict__ U)
{
    int blk = blockIdx.x;
    int b = blk / 17, j = blk - b * 17;
    __shared__ float2 Ys[34 * 32];
    __shared__ float ct[128], st[128];
    int tid = threadIdx.x;
    if (tid < 128) {
        float a = TWO_PI_OVER_128 * (float)tid;
        sincosf(a, &st[tid], &ct[tid]);
    }
    const float2* src = Y + (size_t)blk * (34 * 32);
    for (int i = tid; i < 34 * 32; i += 256) Ys[i] = src[i];
    __syncthreads();
    int o = tid & 31, g = tid >> 5;
    float yr[34], yi[34];
#pragma unroll
    for (int i = 0; i < 34; ++i) { float2 v = Ys[i * 32 + o]; yr[i] = v.x; yi[i] = v.y; }
    for (int xi = 0; xi < 16; ++xi) {
        int xr = (xi << 3) + g;
        float cx = ct[xr], sx = st[xr];
        float cr = 1.f, ci = 0.f, re = 0.f, im = 0.f;
#pragma unroll
        for (int i = 0; i < 17; ++i) {
            re += yr[i] * cr - yi[i] * ci;
            im += yr[i] * ci + yi[i] * cr;
            float nr = cr * cx - ci * sx;
            ci = fmaf(cr, sx, ci * cx);
            cr = nr;
        }
        int k2 = (111 * xr) & 127;
        cr = ct[k2]; ci = st[k2];
#pragma unroll
        for (int i = 17; i < 34; ++i) {
            re += yr[i] * cr - yi[i] * ci;
            im += yr[i] * ci + yi[i] * cr;
            float nr = cr * cx - ci * sx;
            ci = fmaf(cr, sx, ci * cx);
            cr = nr;
        }
        U[(((size_t)(b * 128 + xr)) * 17 + j) * 32 + o] = make_float2(re, im);
    }
}

// ---------------- K4: inverse y-axis c2r, parity-fold quad-output (R6).
__global__ __launch_bounds__(128) void k_inv_y(const float2* __restrict__ U, float* __restrict__ out)
{
    int blk = blockIdx.x;
    __shared__ float2 Us[17 * 32];
    __shared__ float2 cst[128];
    int tid = threadIdx.x;
    {
        float s, c; sincosf(TWO_PI_OVER_128 * (float)tid, &s, &c);
        cst[tid] = make_float2(c, s);
    }
    const float4* src4 = (const float4*)(U + (size_t)blk * 544);
    float4* Us4 = (float4*)Us;
    for (int i = tid; i < 272; i += 128) Us4[i] = src4[i];
    __syncthreads();
    int cg = tid & 15, yg = tid >> 4, c0 = cg << 1;
    float base0, base1;
    {
        float4 v = *(const float4*)&Us[c0];
        base0 = v.x; base1 = v.z;
    }
    float urr[16][2], uii[16][2];
#pragma unroll
    for (int jj = 1; jj <= 16; ++jj) {
        float4 v = *(const float4*)&Us[jj * 32 + c0];
        urr[jj-1][0] = 2.f * v.x; uii[jj-1][0] = 2.f * v.y;
        urr[jj-1][1] = 2.f * v.z; uii[jj-1][1] = 2.f * v.w;
    }
    float* op = out + ((size_t)blk << 12);
    for (int k = 0; k < 4; ++k) {
        int y = 1 + yg + (k << 3);                   // y in 1..32 (y=32 dup, same thread)
        float Ae0=0,Ao0=0,Be0=0,Bo0=0,Ae1=0,Ao1=0,Be1=0,Bo1=0;
        int idx = y;
#pragma unroll
        for (int jj = 0; jj < 16; ++jj) {            // j = jj+1; parity of j
            float2 w = cst[idx];
            if (jj & 1) {                            // j even
                Ae0 = fmaf(urr[jj][0], w.x, Ae0); Be0 = fmaf(uii[jj][0], w.y, Be0);
                Ae1 = fmaf(urr[jj][1], w.x, Ae1); Be1 = fmaf(uii[jj][1], w.y, Be1);
            } else {                                 // j odd
                Ao0 = fmaf(urr[jj][0], w.x, Ao0); Bo0 = fmaf(uii[jj][0], w.y, Bo0);
                Ao1 = fmaf(urr[jj][1], w.x, Ao1); Bo1 = fmaf(uii[jj][1], w.y, Bo1);
            }
            idx = (idx + y) & 127;
        }
        float s0 = Ae0 + Ao0, d0 = Be0 + Bo0, e0 = Ae0 - Ao0, f0 = Be0 - Bo0;
        float s1 = Ae1 + Ao1, d1 = Be1 + Bo1, e1 = Ae1 - Ao1, f1 = Be1 - Bo1;
        *(float2*)&op[(y << 5) + c0]         = make_float2(base0 + s0 - d0, base1 + s1 - d1);
        *(float2*)&op[((128 - y) << 5) + c0] = make_float2(base0 + s0 + d0, base1 + s1 + d1);
        *(float2*)&op[((64 - y) << 5) + c0]  = make_float2(base0 + e0 + f0, base1 + e1 + f1);
        *(float2*)&op[((64 + y) << 5) + c0]  = make_float2(base0 + e0 - f0, base1 + e1 - f1);
    }
    if (yg == 0) {                                   // out[0], out[64]
        float s0 = 0.f, s1 = 0.f, a0 = 0.f, a1 = 0.f;
#pragma unroll
        for (int jj = 0; jj < 16; ++jj) {
            s0 += urr[jj][0]; s1 += urr[jj][1];
            float sg = (jj & 1) ? 1.f : -1.f;        // (-1)^j, j = jj+1
            a0 = fmaf(sg, urr[jj][0], a0); a1 = fmaf(sg, urr[jj][1], a1);
        }
        *(float2*)&op[c0]             = make_float2(base0 + s0, base1 + s1);
        *(float2*)&op[(64 << 5) + c0] = make_float2(base0 + a0, base1 + a1);
    }
}

extern "C" void kernel_launch(void* const* d_in, const int* in_sizes, int n_in,
                              void* d_out, int out_size, void* d_ws, size_t ws_size,
                              hipStream_t stream)
{
    const float* x    = (const float*)d_in[0];
    const float* temb = (const float*)d_in[1];
    const float* w1r  = (const float*)d_in[2];
    const float* w1i  = (const float*)d_in[3];
    const float* w2r  = (const float*)d_in[4];
    const float* w2i  = (const float*)d_in[5];
    const float* k1r  = (const float*)d_in[6];
    const float* k1i  = (const float*)d_in[7];
    const float* k2r  = (const float*)d_in[8];
    const float* k2i  = (const float*)d_in[9];
    float* out = (float*)d_out;

    char* ws = (char*)d_ws;
    const size_t T1_BYTES = 17825792;                  // 32*17*128*32 float2
    const size_t NEED_FUSED = 2 * T1_BYTES + 8704;     // T1 + U (+ slack)

    if (ws_size >= NEED_FUSED) {
        float2* T1 = (float2*)ws;
        float2* U  = (float2*)(ws + T1_BYTES);
        k_fwd_y    <<<4096, 64,  0, stream>>>(x, T1);
        k_mid_fused<<<544,  512, 0, stream>>>(T1, w1r, w1i, w2r, w2i,
                                              temb, k1r, k1i, k2r, k2i, U);
        k_inv_y    <<<4096, 128, 0, stream>>>(U, out);
    } else {
        float2* T1 = (float2*)ws;
        float2* Yb = (float2*)(ws + T1_BYTES);
        float*  tb = (float*)(ws + T1_BYTES + 4734976);
        float2* U  = T1;
        k_tproj    <<<32,   128, 0, stream>>>(temb, k1r, k1i, k2r, k2i, tb);
        k_fwd_y    <<<4096, 64,  0, stream>>>(x, T1);
        k_fwd_x_mix<<<544,  256, 0, stream>>>(T1, w1r, w1i, w2r, w2i, tb, Yb);
        k_inv_x    <<<544,  256, 0, stream>>>(Yb, U);
        k_inv_y    <<<4096, 128, 0, stream>>>(U, out);
    }
}